// Round 12
// baseline (1629.947 us; speedup 1.0000x reference)
//
#include <hip/hip_runtime.h>
#include <hip/hip_bf16.h>

typedef __attribute__((ext_vector_type(8))) short short8;
typedef __attribute__((ext_vector_type(4))) float f32x4;

// ---------------- problem constants ----------------
static constexpr int kNE  = 200000;   // emails
static constexpr int kNU  = 100000;   // users
static constexpr int kE   = 1000000;  // edges per type
static constexpr int kGrpU = kNE / 8; // 25000 (exact)
static constexpr int kGrpE = kNU / 8; // 12500 (exact)

// ---------------- workspace layout (4-byte element offsets) ----------------
// HARD CONSTRAINT (r5, r7): ws_size = 256 MiB = 268,435,456 B.
static constexpr long long SZ_NEH = (long long)kNE * 128;  // 25.6M
static constexpr long long SZ_NUH = (long long)kNU * 128;  // 12.8M
static constexpr long long O_B0   = 64;
static constexpr long long O_B1   = O_B0 + SZ_NEH;
static constexpr long long O_B2   = O_B1 + SZ_NEH;
static constexpr long long O_W    = O_B2 + SZ_NUH;
static constexpr long long O_BEM  = O_W;                   // 128
static constexpr long long O_BL1  = O_BEM + 128;           // 128
static constexpr long long O_BEN  = O_BL1 + 128;           // 128
static constexpr long long O_BL2  = O_BEN + 128;           // 128
static constexpr long long O_GRID1= O_BL2 + 128;           // 1536
static constexpr long long O_BASE2= O_GRID1 + 1536;        // 128
static constexpr long long O_GRID2= O_BASE2 + 128;         // 768
static constexpr long long O_SW2  = O_GRID2 + 768;         // 1024
// int region
static constexpr long long I_CNT_UE = O_SW2 + 1024;
static constexpr long long I_CNT_EU = I_CNT_UE + kNE;
static constexpr long long I_RO_UE  = I_CNT_EU + kNU;
static constexpr long long I_RO_EU  = I_RO_UE + kNE;
static constexpr long long I_CUR_UE = I_RO_EU + kNU;
static constexpr long long I_CUR_EU = I_CUR_UE + kNE;
static constexpr long long I_SRT_UE = I_CUR_EU + kNU;
static constexpr long long I_SRT_EU = I_SRT_UE + kE;
static constexpr long long I_BSUM_UE= I_SRT_EU + kE;
static constexpr long long I_BOFF_UE= I_BSUM_UE + 256;
static constexpr long long I_BSUM_EU= I_BOFF_UE + 256;
static constexpr long long I_BOFF_EU= I_BSUM_EU + 256;
static constexpr long long FR_BASE_I= (I_BOFF_EU + 256 + 7) & ~7LL;  // = 66,905,056
// bf16 MFMA B-fragment region (ushort offsets from fbase); total 245,760 ushorts
static constexpr long long U_WEM   = 0;
static constexpr long long U_W1N   = U_WEM + 8192;
static constexpr long long U_W1R   = U_W1N + 16384;
static constexpr long long U_WEN   = U_W1R + 16384;
static constexpr long long U_WER   = U_WEN + 16384;
static constexpr long long U_W2N   = U_WER + 16384;
static constexpr long long U_W2R   = U_W2N + 16384;
static constexpr long long U_BASE1 = U_W2R + 16384;
static constexpr long long U_SW1H  = U_BASE1 + 8192;
static constexpr long long U_SW1L  = U_SW1H + 65536;

__device__ __forceinline__ float bf2f(unsigned short u) {
    return __uint_as_float(((unsigned)u) << 16);
}
__device__ __forceinline__ unsigned short f2bf_rne(float f) {
    unsigned u = __float_as_uint(f);
    return (unsigned short)((u + 0x7fffu + ((u >> 16) & 1u)) >> 16);
}
__device__ __forceinline__ void split2(float x, unsigned short& hi, unsigned short& lo) {
    hi = f2bf_rne(x);
    lo = f2bf_rne(x - bf2f(hi));
}
// ---- r14: truncation split (activations only; weights keep rne in prep) ----
__device__ __forceinline__ float btrunc(float x) {
    return __uint_as_float(__float_as_uint(x) & 0xffff0000u);
}
// pack top-16-bits of two floats: low16 = bf16t(x0), high16 = bf16t(x1) (1 v_perm)
__device__ __forceinline__ unsigned pack_hi2(float x0, float x1) {
    return __builtin_amdgcn_perm(__float_as_uint(x1), __float_as_uint(x0), 0x07060302u);
}
// trunc-split 8 floats into hi/lo short8 fragments (8 and + 8 sub + 8 perm)
__device__ __forceinline__ void split8_trunc(const float* __restrict__ xv, short8& ah, short8& al) {
    unsigned* hp = (unsigned*)&ah;
    unsigned* lp = (unsigned*)&al;
#pragma unroll
    for (int jp = 0; jp < 4; jp++) {
        const float x0 = xv[2 * jp], x1 = xv[2 * jp + 1];
        const float l0 = x0 - btrunc(x0), l1 = x1 - btrunc(x1);
        hp[jp] = pack_hi2(x0, x1);
        lp[jp] = pack_hi2(l0, l1);
    }
}
// dtype probe: grid1[0] as fp32 is -2.2f (0xC00CCCCD); else storage is bf16.
__device__ __forceinline__ int get_isbf(const unsigned* __restrict__ g) {
    return (g[0] == 0xC00CCCCDu) ? 0 : 1;
}

// ================= fused prep (verified r9) =================
__device__ __forceinline__ void pack128_one(const void* __restrict__ src, unsigned short* __restrict__ dst,
                                            int K, int t, int isbf) {
    const int lane = t & 63;
    const int nt = (t >> 6) % 8;
    const int kt = (t >> 6) / 8;
    const int n = nt * 16 + (lane & 15);
    const int k0 = kt * 32 + (lane >> 4) * 8;
    unsigned short* d = dst + (((size_t)(kt * 8 + nt) * 64 + lane) << 3);
#pragma unroll
    for (int j = 0; j < 8; j++) {
        float f = isbf ? bf2f(((const unsigned short*)src)[(size_t)n * K + k0 + j])
                       : ((const float*)src)[(size_t)n * K + k0 + j];
        d[j] = f2bf_rne(f);
    }
}

__device__ __forceinline__ void base1_one(const void* __restrict__ src, unsigned short* __restrict__ dst,
                                          int t, int isbf) {
    const int lane = t & 63, nt = (t >> 6) & 3, kt = t >> 8;
    const int n = nt * 16 + (lane & 15);
    const int k0 = kt * 32 + (lane >> 4) * 8;
    unsigned short* d = dst + (((size_t)(kt * 4 + nt) * 64 + lane) << 3);
#pragma unroll
    for (int j = 0; j < 8; j++) {
        float f = isbf ? bf2f(((const unsigned short*)src)[n * 128 + k0 + j])
                       : ((const float*)src)[n * 128 + k0 + j];
        d[j] = f2bf_rne(f);
    }
}

__device__ __forceinline__ void sw1_one(const void* __restrict__ sp, const void* __restrict__ sc,
                                        unsigned short* __restrict__ dh, unsigned short* __restrict__ dl,
                                        int t, int isbf) {
    const int lane = t & 63, nt = (t >> 6) & 3, kt = t >> 8;
    const int n = nt * 16 + (lane & 15);
    const int k0 = kt * 32 + (lane >> 4) * 8;
    const float scal = isbf ? bf2f(((const unsigned short*)sc)[n * 128 + (k0 >> 3)])
                            : ((const float*)sc)[n * 128 + (k0 >> 3)];
    const size_t base = ((size_t)(kt * 4 + nt) * 64 + lane) << 3;
#pragma unroll
    for (int j = 0; j < 8; j++) {
        float f = isbf ? bf2f(((const unsigned short*)sp)[(size_t)n * 1024 + k0 + j])
                       : ((const float*)sp)[(size_t)n * 1024 + k0 + j];
        float p = f * scal;
        unsigned short hi, lo;
        split2(p, hi, lo);
        dh[base + j] = hi;
        dl[base + j] = lo;
    }
}

struct PrepArgs {
    const void* csrc[7];  int coff[7];  int cn[7];
    const void* psrc[7];  unsigned pdst[7];  int pK[7];
    const void* sp2;  const void* sc2;
    const void* b1src;  const void* swsp;  const void* swsc;
};

__global__ __launch_bounds__(256) void prep_kernel(PrepArgs A, float* __restrict__ wsf,
                                                   int* __restrict__ wsi,
                                                   unsigned short* __restrict__ fbase,
                                                   const unsigned* __restrict__ gdet) {
    const int isbf = get_isbf(gdet);
    const int t0 = blockIdx.x * 256 + threadIdx.x;
    const int gs = gridDim.x * 256;
    for (int i = t0; i < kNE + kNU; i += gs) wsi[I_CNT_UE + i] = 0;
    for (int t = 0; t < 7; t++) {
        const int n = A.cn[t];
        const void* s = A.csrc[t];
        float* d = wsf + A.coff[t];
        for (int i = t0; i < n; i += gs)
            d[i] = isbf ? bf2f(((const unsigned short*)s)[i]) : ((const float*)s)[i];
    }
    for (int i = t0; i < 1024; i += gs) {
        float a = isbf ? bf2f(((const unsigned short*)A.sp2)[i]) : ((const float*)A.sp2)[i];
        float b = isbf ? bf2f(((const unsigned short*)A.sc2)[i >> 3]) : ((const float*)A.sc2)[i >> 3];
        wsf[O_SW2 + i] = a * b;
    }
    for (int t = 0; t < 7; t++) {
        const int K = A.pK[t];
        const int tot = (K / 32) * 8 * 64;
        unsigned short* dst = fbase + A.pdst[t];
        const void* src = A.psrc[t];
        for (int i = t0; i < tot; i += gs) pack128_one(src, dst, K, i, isbf);
    }
    for (int i = t0; i < 1024; i += gs) base1_one(A.b1src, fbase + U_BASE1, i, isbf);
    for (int i = t0; i < 8192; i += gs)
        sw1_one(A.swsp, A.swsc, fbase + U_SW1H, fbase + U_SW1L, i, isbf);
}

// ================= fused CSR build (r17 verified: XCD-partitioned) =================
__global__ __launch_bounds__(256) void hist_both(const int* __restrict__ ue, const int* __restrict__ eu,
                                                 int* __restrict__ cntU, int* __restrict__ cntE) {
    const int g = blockIdx.x & 7;
    const int loU = g * kGrpU, hiU = loU + kGrpU;
    const int loE = g * kGrpE, hiE = loE + kGrpE;
    const int stride = (gridDim.x >> 3) * 256;
    for (int i = (blockIdx.x >> 3) * 256 + threadIdx.x; i < kE; i += stride) {
        const int d = ue[kE + i];
        if (d >= loU && d < hiU) atomicAdd(&cntU[d], 1);
        const int d2 = eu[kE + i];
        if (d2 >= loE && d2 < hiE) atomicAdd(&cntE[d2], 1);
    }
}

__global__ __launch_bounds__(256) void scan1_both(const int* __restrict__ cntU, int* __restrict__ roU,
                                                  int* __restrict__ bsU, const int* __restrict__ cntE,
                                                  int* __restrict__ roE, int* __restrict__ bsE) {
    __shared__ int sc[256];
    int b = blockIdx.x;
    const int* cnt;  int* ro;  int* bsum;  int n;
    if (b < 196) { cnt = cntU; ro = roU; bsum = bsU; n = kNE; }
    else { b -= 196; cnt = cntE; ro = roE; bsum = bsE; n = kNU; }
    const int t = threadIdx.x;
    const int i0 = b * 1024 + t * 4;
    int c[4];
#pragma unroll
    for (int q = 0; q < 4; q++) c[q] = (i0 + q < n) ? cnt[i0 + q] : 0;
    int s = c[0] + c[1] + c[2] + c[3];
    sc[t] = s;
    __syncthreads();
    for (int off = 1; off < 256; off <<= 1) {
        int v = (t >= off) ? sc[t - off] : 0;
        __syncthreads();
        sc[t] += v;
        __syncthreads();
    }
    int run = sc[t] - s;
#pragma unroll
    for (int q = 0; q < 4; q++) {
        if (i0 + q < n) ro[i0 + q] = run;
        run += c[q];
    }
    if (t == 255) bsum[b] = sc[255];
}

__global__ __launch_bounds__(256) void scan2_both(const int* __restrict__ bsU, int* __restrict__ boU,
                                                  const int* __restrict__ bsE, int* __restrict__ boE) {
    __shared__ int sc[256];
    const int* bsum;  int* boff;  int nb;
    if (blockIdx.x == 0) { bsum = bsU; boff = boU; nb = 196; }
    else { bsum = bsE; boff = boE; nb = 98; }
    const int t = threadIdx.x;
    int s = (t < nb) ? bsum[t] : 0;
    sc[t] = s;
    __syncthreads();
    for (int off = 1; off < 256; off <<= 1) {
        int v = (t >= off) ? sc[t - off] : 0;
        __syncthreads();
        sc[t] += v;
        __syncthreads();
    }
    if (t < nb) boff[t] = sc[t] - s;
}

__global__ __launch_bounds__(256) void scan3_both(int* __restrict__ roU, int* __restrict__ curU,
                                                  const int* __restrict__ boU, int* __restrict__ roE,
                                                  int* __restrict__ curE, const int* __restrict__ boE) {
    const int stride = gridDim.x * blockDim.x;
    for (int i = blockIdx.x * blockDim.x + threadIdx.x; i < kNE + kNU; i += stride) {
        if (i < kNE) {
            int v = roU[i] + boU[i >> 10];
            roU[i] = v;
            curU[i] = v;
        } else {
            int j = i - kNE;
            int v = roE[j] + boE[j >> 10];
            roE[j] = v;
            curE[j] = v;
        }
    }
}

__global__ __launch_bounds__(256) void fill_both(const int* __restrict__ ue, const int* __restrict__ eu,
                                                 int* __restrict__ curU, int* __restrict__ srtU,
                                                 int* __restrict__ curE, int* __restrict__ srtE) {
    const int g = blockIdx.x & 7;
    const int loU = g * kGrpU, hiU = loU + kGrpU;
    const int loE = g * kGrpE, hiE = loE + kGrpE;
    const int stride = (gridDim.x >> 3) * 256;
    for (int i = (blockIdx.x >> 3) * 256 + threadIdx.x; i < kE; i += stride) {
        const int d = ue[kE + i];
        if (d >= loU && d < hiU) {
            const int pos = atomicAdd(&curU[d], 1);
            srtU[pos] = ue[i];
        }
        const int d2 = eu[kE + i];
        if (d2 >= loE && d2 < hiE) {
            const int pos = atomicAdd(&curE[d2], 1);
            srtE[pos] = eu[i];
        }
    }
}

// ================= LDS staging (r12: THREADS-templated) =================
template <int KD, bool RAW, int THREADS>
__device__ __forceinline__ void stage_tile(float (*Xs)[132], const void* __restrict__ Av, int r0, int N,
                                           int tid, int isbf) {
    constexpr int TPR = THREADS / 64;   // threads per row
    constexpr int per = KD / TPR;       // floats per thread (16 or 32)
    const int row = tid / TPR;
    const int cq = (tid % TPR) * per;
    const size_t gr = (size_t)min(r0 + row, N - 1);
    if (RAW && isbf) {
        const unsigned short* p = (const unsigned short*)Av + gr * KD + cq;
#pragma unroll
        for (int v = 0; v < per; v += 8) {
            short8 s = *(const short8*)(p + v);
#pragma unroll
            for (int j = 0; j < 8; j++) Xs[row][cq + v + j] = bf2f(((unsigned short*)&s)[j]);
        }
    } else {
        const float* p = (const float*)Av + gr * KD + cq;
#pragma unroll
        for (int v = 0; v < per; v += 4) *(float4*)&Xs[row][cq + v] = *(const float4*)(p + v);
    }
}

// split-bf16 GEMM phase body (r14: trunc-split, 24 ops vs ~80 for rne-split)
template <int KT, int NT>
__device__ __forceinline__ void gemm_phase(float (*Xs)[132], const unsigned short* __restrict__ Wf,
                                           f32x4* acc, int rowl, int q, int lane, int ntBase) {
#pragma unroll
    for (int kt = 0; kt < KT; kt++) {
        float xv[8];
        *(float4*)&xv[0] = *(const float4*)&Xs[rowl][kt * 32 + q * 8];
        *(float4*)&xv[4] = *(const float4*)&Xs[rowl][kt * 32 + q * 8 + 4];
        short8 ah, al;
        split8_trunc(xv, ah, al);
#pragma unroll
        for (int nt = 0; nt < NT; nt++) {
            short8 b = *(const short8*)(Wf + (((size_t)(kt * 8 + ntBase + nt) * 64 + lane) << 3));
            acc[nt] = __builtin_amdgcn_mfma_f32_16x16x32_bf16(ah, b, acc[nt], 0, 0, 0);
            acc[nt] = __builtin_amdgcn_mfma_f32_16x16x32_bf16(al, b, acc[nt], 0, 0, 0);
        }
    }
}

// ================= lin_xe (verified r9) =================
__global__ __launch_bounds__(256) void lin_xe(const void* __restrict__ A1,
                                              const unsigned short* __restrict__ W1f,
                                              const float* __restrict__ bias, float* __restrict__ out, int N,
                                              const unsigned* __restrict__ gdet) {
    __shared__ float Xs[64][132];
    const int tid = threadIdx.x;
    const int wave = tid >> 6, lane = tid & 63;
    const int m = lane & 15, q = lane >> 4;
    const int r0 = blockIdx.x * 64;
    const int isbf = get_isbf(gdet);
    const int rowl = wave * 16 + m;
    f32x4 acc[8] = {};

    stage_tile<64, true, 256>(Xs, A1, r0, N, tid, isbf);
    __syncthreads();
    gemm_phase<2, 8>(Xs, W1f, acc, rowl, q, lane, 0);

    float bv[8];
#pragma unroll
    for (int nt = 0; nt < 8; nt++) bv[nt] = bias[nt * 16 + m];
#pragma unroll
    for (int r = 0; r < 4; r++) {
        int grow = r0 + wave * 16 + q * 4 + r;
        if (grow < N) {
#pragma unroll
            for (int nt = 0; nt < 8; nt++)
                out[(size_t)grow * 128 + nt * 16 + m] = acc[nt][r] + bv[nt];
        }
    }
}

// gather row load helper (r12)
template <bool RAWG>
__device__ __forceinline__ float2 gload(const void* __restrict__ G, int s, int lane, int isbf) {
    if (RAWG && isbf) {
        const ushort2 v = *(const ushort2*)((const unsigned short*)G + (size_t)s * 128 + lane * 2);
        return make_float2(bf2f(v.x), bf2f(v.y));
    }
    return *(const float2*)((const float*)G + (size_t)s * 128 + lane * 2);
}

// ================= fused agg + dual GEMM =================
// r12/r13/r17/r19 verified: 512-thread blocks, wave = (row-group wg) x
// (col-half wh), acc[4], per-row 4-deep edge unroll, CSR bounds preloaded.
template <bool RAWG, bool RAW2>
__global__ __launch_bounds__(512, 8) void agglin_mfma(const void* __restrict__ Gsrc, const void* __restrict__ A2,
                                                   const unsigned short* __restrict__ W1f,
                                                   const unsigned short* __restrict__ W2f,
                                                   const float* __restrict__ bias, float* __restrict__ out,
                                                   const int* __restrict__ ro, const int* __restrict__ cnt,
                                                   const int* __restrict__ sorted, int N,
                                                   const unsigned* __restrict__ gdet) {
    __shared__ float Xs[64][132];
    const int tid = threadIdx.x;
    const int wave = tid >> 6, lane = tid & 63;
    const int m = lane & 15, q = lane >> 4;
    const int wg = wave >> 1;   // row-group 0..3 (16 rows each)
    const int wh = wave & 1;    // col-half 0..1 (4 nt each)
    const int r0 = blockIdx.x * 64;
    const int isbf = get_isbf(gdet);

    // preload CSR bounds for the wave's 8 rows (r19: independent loads up-front)
    int beg8[8], cnt8[8];
#pragma unroll
    for (int rr = 0; rr < 8; rr++) {
        const int n = r0 + wave * 8 + rr;
        beg8[rr] = (n < N) ? ro[n] : 0;
        cnt8[rr] = (n < N) ? cnt[n] : 0;
    }

    // gather phase: wave w computes means of rows w*8..w*8+7 into Xs (r12 form).
#pragma unroll 1
    for (int rr = 0; rr < 8; rr++) {
        const int lrow = wave * 8 + rr;
        const int beg = beg8[rr];
        const int end = beg + cnt8[rr];
        float ax = 0.f, ay = 0.f;
        float a1x = 0.f, a1y = 0.f, a2x = 0.f, a2y = 0.f, a3x = 0.f, a3y = 0.f;
        int p = beg;
        for (; p + 3 < end; p += 4) {
            const int s0 = sorted[p], s1 = sorted[p + 1], s2 = sorted[p + 2], s3 = sorted[p + 3];
            const float2 v0 = gload<RAWG>(Gsrc, s0, lane, isbf);
            const float2 v1 = gload<RAWG>(Gsrc, s1, lane, isbf);
            const float2 v2 = gload<RAWG>(Gsrc, s2, lane, isbf);
            const float2 v3 = gload<RAWG>(Gsrc, s3, lane, isbf);
            ax += v0.x;  ay += v0.y;
            a1x += v1.x; a1y += v1.y;
            a2x += v2.x; a2y += v2.y;
            a3x += v3.x; a3y += v3.y;
        }
        for (; p < end; p++) {
            const float2 v = gload<RAWG>(Gsrc, sorted[p], lane, isbf);
            ax += v.x;
            ay += v.y;
        }
        ax += a1x + a2x + a3x;
        ay += a1y + a2y + a3y;
        const int deg = end - beg;
        const float inv = (deg > 0) ? 1.f / (float)deg : 0.f;
        Xs[lrow][lane * 2] = ax * inv;
        Xs[lrow][lane * 2 + 1] = ay * inv;
    }
    __syncthreads();

    const int rowl = wg * 16 + m;
    const int ntBase = wh * 4;
    f32x4 acc[4] = {};

    // phase 1: mean @ W1^T
    gemm_phase<4, 4>(Xs, W1f, acc, rowl, q, lane, ntBase);

    // phase 2: + A2 @ W2^T
    __syncthreads();
    stage_tile<128, RAW2, 512>(Xs, A2, r0, N, tid, isbf);
    __syncthreads();
    gemm_phase<4, 4>(Xs, W2f, acc, rowl, q, lane, ntBase);

    // epilogue
    float bv[4];
#pragma unroll
    for (int nt = 0; nt < 4; nt++) bv[nt] = bias[(ntBase + nt) * 16 + m];
#pragma unroll
    for (int r = 0; r < 4; r++) {
        int grow = r0 + wg * 16 + q * 4 + r;
        if (grow < N) {
#pragma unroll
            for (int nt = 0; nt < 4; nt++) {
                float v = acc[nt][r] + bv[nt];
                out[(size_t)grow * 128 + (ntBase + nt) * 16 + m] = fmaxf(v, 0.f);
            }
        }
    }
}

// ================= uniform-knot Cox-de Boor collapse (r11) =================
// Scalar version (kan2 uses float bases + FMA, no fragments)
__device__ __forceinline__ void bases8u(float x, float t0, float invh, float* __restrict__ b) {
    const float sp = (x - t0) * invh;
    const float fi = floorf(sp);
    const float u = sp - fi;
    const int i = (int)fi;
    const float u2 = u * u, u3 = u2 * u;
    const float v = 1.f - u;
    const float p0 = u3 * (1.f / 6.f);
    const float p1 = fmaf(-0.5f, u3, fmaf(0.5f, u2, fmaf(0.5f, u, 1.f / 6.f)));
    const float p2 = fmaf(0.5f, u3, fmaf(-1.f, u2, 2.f / 3.f));
    const float p3 = v * v * v * (1.f / 6.f);
#pragma unroll
    for (int j = 0; j < 8; j++) {
        float r = (i == j) ? p0 : 0.f;
        r = (i == j + 1) ? p1 : r;
        r = (i == j + 2) ? p2 : r;
        r = (i == j + 3) ? p3 : r;
        b[j] = r;
    }
}

// ---- r15: fragment-direct funnel-shift scatter (verified r15 run) ----
__device__ __forceinline__ void bases8u_frag(float x, float t0, float invh, short8& bh, short8& bl) {
    const float sp = (x - t0) * invh;
    const float fi = floorf(sp);
    const float u = sp - fi;
    int i = (int)fi;
    i = max(-1, min(11, i));
    const float u2 = u * u, u3 = u2 * u;
    const float v = 1.f - u;
    const float p0 = u3 * (1.f / 6.f);
    const float p1 = fmaf(-0.5f, u3, fmaf(0.5f, u2, fmaf(0.5f, u, 1.f / 6.f)));
    const float p2 = fmaf(0.5f, u3, fmaf(-1.f, u2, 2.f / 3.f));
    const float p3 = v * (v * v) * (1.f / 6.f);
    const float q0 = p0 - btrunc(p0), q1 = p1 - btrunc(p1);
    const float q2 = p2 - btrunc(p2), q3 = p3 - btrunc(p3);
    // little-endian: bits[0:15]=p3, [16:31]=p2, [32:47]=p1, [48:63]=p0
    const unsigned long long Ph = (((unsigned long long)pack_hi2(p1, p0)) << 32) | pack_hi2(p3, p2);
    const unsigned long long Pl = (((unsigned long long)pack_hi2(q1, q0)) << 32) | pack_hi2(q3, q2);
    const int t = 16 * i - 48;  // in [-64, 128], multiple of 16
    const unsigned sa = (unsigned)t & 63u;
    const unsigned sb = (unsigned)(-t) & 63u;
    const unsigned sc = (unsigned)(64 - t) & 63u;
    const unsigned sd = (unsigned)(t - 64) & 63u;
    const bool neg = t < 0;
    const bool ok0 = t >= -48;
    const bool lt64 = t < 64;
    const bool gt0 = t > 0;
    const bool lt128 = t < 128;
    const unsigned long long h0 = neg ? (ok0 ? (Ph >> sb) : 0ull) : (lt64 ? (Ph << sa) : 0ull);
    const unsigned long long h1 = neg ? 0ull : (lt64 ? (gt0 ? (Ph >> sc) : 0ull)
                                                     : (lt128 ? (Ph << sd) : 0ull));
    const unsigned long long g0 = neg ? (ok0 ? (Pl >> sb) : 0ull) : (lt64 ? (Pl << sa) : 0ull);
    const unsigned long long g1 = neg ? 0ull : (lt64 ? (gt0 ? (Pl >> sc) : 0ull)
                                                     : (lt128 ? (Pl << sd) : 0ull));
    unsigned long long* bhp = (unsigned long long*)&bh;
    unsigned long long* blp = (unsigned long long*)&bl;
    bhp[0] = h0; bhp[1] = h1;
    blp[0] = g0; blp[1] = g1;
}

// ================= KAN layer 1 =================
// r14: XOR-swizzled unpadded LDS [64][128]; trunc-split. r15: funnel-shift
// fragment-direct bases. r16: phase-B ping-pong weight prefetch. r20: K-SPLIT
// 512-thread blocks — wave = (row-group wg2 0..3) x (K-half kh 0..1); each
// pair member computes the same 16 rows over half the K range (A: 2 of 4 kt;
// B: 16 of 32 kt); kh=1 partials reduced through (dead) Xs LDS at stride 20
// floats (bank-rotating). Doubles waves/CU (r19 measured 37.5% occupancy,
// VALUBusy 48% — TLP-starved); total VALU/MFMA work unchanged.
__global__ __launch_bounds__(512, 8) void kan1_mfma(const float* __restrict__ X,
                                                 const unsigned short* __restrict__ basef,
                                                 const unsigned short* __restrict__ swh,
                                                 const unsigned short* __restrict__ swl,
                                                 const float* __restrict__ grid, float* __restrict__ Hout) {
    __shared__ float Xs[64][128];
    const int tid = threadIdx.x;
    const int wave = tid >> 6, lane = tid & 63;
    const int m = lane & 15, q = lane >> 4;
    const int wg2 = wave >> 1;  // row-group 0..3 (16 rows each)
    const int kh = wave & 1;    // K-half 0..1
    const int r0 = blockIdx.x * 64;

    const float t0 = grid[0];
    const float invh = 1.f / (grid[1] - grid[0]);

    {
        const int row = tid >> 3, cq = (tid & 7) * 16;
        const int sw = (row & 7) << 2;
        const float* p = &X[(size_t)(r0 + row) * 128 + cq];
#pragma unroll
        for (int v = 0; v < 4; v++) *(float4*)&Xs[row][(cq + v * 4) ^ sw] = *(const float4*)(p + v * 4);
    }
    __syncthreads();

    const int rowl = wg2 * 16 + m;
    const int swr = (rowl & 7) << 2;
    f32x4 acc[4] = {};

    // phase A: silu(x) @ base1^T (K=128); this wave does kt = 2*kh, 2*kh+1
#pragma unroll
    for (int kk = 0; kk < 2; kk++) {
        const int kt = kh * 2 + kk;
        float xv[8];
        *(float4*)&xv[0] = *(const float4*)&Xs[rowl][(kt * 32 + q * 8) ^ swr];
        *(float4*)&xv[4] = *(const float4*)&Xs[rowl][(kt * 32 + q * 8 + 4) ^ swr];
        float sv[8];
#pragma unroll
        for (int j = 0; j < 8; j++) {
            float x = xv[j];
            sv[j] = x / (1.f + __expf(-x));
        }
        short8 ah, al;
        split8_trunc(sv, ah, al);
#pragma unroll
        for (int nt = 0; nt < 4; nt++) {
            short8 b = *(const short8*)(basef + (((size_t)(kt * 4 + nt) * 64 + lane) << 3));
            acc[nt] = __builtin_amdgcn_mfma_f32_16x16x32_bf16(ah, b, acc[nt], 0, 0, 0);
            acc[nt] = __builtin_amdgcn_mfma_f32_16x16x32_bf16(al, b, acc[nt], 0, 0, 0);
        }
    }

    // phase B: spline GEMM; this wave does kt = kh*16 .. kh*16+15.
    // Fragment address (kt,nt): (kt*2048 + nt*512 + lane*8) ushorts.
    const int ktBase = kh * 16;
    const unsigned short* __restrict__ whp = swh + ((size_t)ktBase * 2048) + ((size_t)lane << 3);
    const unsigned short* __restrict__ wlp = swl + ((size_t)ktBase * 2048) + ((size_t)lane << 3);
    short8 wAh[4], wAl[4], wBh[4], wBl[4];
#pragma unroll
    for (int nt = 0; nt < 4; nt++) {
        wAh[nt] = *(const short8*)(whp + nt * 512);
        wAl[nt] = *(const short8*)(wlp + nt * 512);
    }
    float xE = Xs[rowl][(ktBase * 4 + q) ^ swr];
#pragma unroll 1
    for (int kt2 = 0; kt2 < 8; kt2++) {
        const int ko = 2 * kt2 + 1;  // relative odd kt
        // prefetch odd-kt weights (independent of even compute below)
#pragma unroll
        for (int nt = 0; nt < 4; nt++) {
            wBh[nt] = *(const short8*)(whp + ko * 2048 + nt * 512);
            wBl[nt] = *(const short8*)(wlp + ko * 2048 + nt * 512);
        }
        const float xO = Xs[rowl][((ktBase + ko) * 4 + q) ^ swr];
        // compute even kt with buffer A
        {
            short8 bh, bl;
            bases8u_frag(xE, t0, invh, bh, bl);
#pragma unroll
            for (int nt = 0; nt < 4; nt++) {
                acc[nt] = __builtin_amdgcn_mfma_f32_16x16x32_bf16(bh, wAh[nt], acc[nt], 0, 0, 0);
                acc[nt] = __builtin_amdgcn_mfma_f32_16x16x32_bf16(bl, wAh[nt], acc[nt], 0, 0, 0);
                acc[nt] = __builtin_amdgcn_mfma_f32_16x16x32_bf16(bh, wAl[nt], acc[nt], 0, 0, 0);
            }
        }
        // prefetch next even-kt weights
        if (kt2 < 7) {
            const int ke2 = 2 * kt2 + 2;
#pragma unroll
            for (int nt = 0; nt < 4; nt++) {
                wAh[nt] = *(const short8*)(whp + ke2 * 2048 + nt * 512);
                wAl[nt] = *(const short8*)(wlp + ke2 * 2048 + nt * 512);
            }
            xE = Xs[rowl][((ktBase + ke2) * 4 + q) ^ swr];
        }
        // compute odd kt with buffer B
        {
            short8 bh, bl;
            bases8u_frag(xO, t0, invh, bh, bl);
#pragma unroll
            for (int nt = 0; nt < 4; nt++) {
                acc[nt] = __builtin_amdgcn_mfma_f32_16x16x32_bf16(bh, wBh[nt], acc[nt], 0, 0, 0);
                acc[nt] = __builtin_amdgcn_mfma_f32_16x16x32_bf16(bl, wBh[nt], acc[nt], 0, 0, 0);
                acc[nt] = __builtin_amdgcn_mfma_f32_16x16x32_bf16(bh, wBl[nt], acc[nt], 0, 0, 0);
            }
        }
    }

    // r20: K-half reduction through LDS (Xs dead now). Stride 20 floats
    // (bank-rotating); max offset (3*64+63)*20+16 = 5116 < 8192 floats.
    __syncthreads();
    float* red = &Xs[0][0];
    const int rb = (wg2 * 64 + lane) * 20;
    if (kh == 1) {
#pragma unroll
        for (int nt = 0; nt < 4; nt++) *(f32x4*)&red[rb + nt * 4] = acc[nt];
    }
    __syncthreads();
    if (kh == 0) {
#pragma unroll
        for (int nt = 0; nt < 4; nt++) {
            const f32x4 pv = *(const f32x4*)&red[rb + nt * 4];
            acc[nt] += pv;
        }
#pragma unroll
        for (int r = 0; r < 4; r++) {
            int grow = r0 + wg2 * 16 + q * 4 + r;
#pragma unroll
            for (int nt = 0; nt < 4; nt++) Hout[(size_t)grow * 64 + nt * 16 + m] = acc[nt][r];
        }
    }
}

// ================= KAN layer 2 =================
__global__ __launch_bounds__(256) void kan2_kernel(const float* __restrict__ h, const float* __restrict__ base2,
                                                   const float* __restrict__ sw2, const float* __restrict__ grid2,
                                                   void* __restrict__ out, const unsigned* __restrict__ gdet) {
    const int lane = threadIdx.x & 63;
    const int wid = (blockIdx.x * blockDim.x + threadIdx.x) >> 6;
    const int nw = (gridDim.x * blockDim.x) >> 6;
    const int k = lane;
    const float t0 = grid2[0];
    const float invh = 1.f / (grid2[1] - grid2[0]);
    const float wb0 = base2[k], wb1 = base2[64 + k];
    float ws0[8], ws1[8];
#pragma unroll
    for (int j = 0; j < 8; j++) { ws0[j] = sw2[k * 8 + j]; ws1[j] = sw2[512 + k * 8 + j]; }
    const int isbf = get_isbf(gdet);

    for (int n = wid; n < kNE; n += nw) {
        float x = h[(size_t)n * 64 + k];
        float sil = x / (1.f + __expf(-x));
        float b[8];
        bases8u(x, t0, invh, b);
        float o0 = sil * wb0, o1 = sil * wb1;
#pragma unroll
        for (int j = 0; j < 8; j++) {
            o0 = fmaf(b[j], ws0[j], o0);
            o1 = fmaf(b[j], ws1[j], o1);
        }
#pragma unroll
        for (int off = 32; off > 0; off >>= 1) {
            o0 += __shfl_down(o0, off, 64);
            o1 += __shfl_down(o1, off, 64);
        }
        if (lane == 0) {
            if (isbf) {
                __hip_bfloat16* ob = (__hip_bfloat16*)out;
                ob[(size_t)n * 2] = __float2bfloat16(o0);
                ob[(size_t)n * 2 + 1] = __float2bfloat16(o1);
            } else {
                ((float2*)out)[n] = make_float2(o0, o1);
            }
        }
    }
}

// ================= launch =================
extern "C" void kernel_launch(void* const* d_in, const int* in_sizes, int n_in, void* d_out, int out_size,
                              void* d_ws, size_t ws_size, hipStream_t stream) {
    (void)in_sizes; (void)n_in; (void)out_size; (void)ws_size;
    float* wsf = (float*)d_ws;
    int* wsi = (int*)d_ws;
    unsigned short* fbase = (unsigned short*)(wsi + FR_BASE_I);
    const unsigned* gdet = (const unsigned*)d_in[21];

    PrepArgs A;
    const int csrc[7] = {4, 7, 10, 13, 21, 22, 25};
    const long long coff[7] = {O_BEM, O_BL1, O_BEN, O_BL2, O_GRID1, O_BASE2, O_GRID2};
    const int cn[7] = {128, 128, 128, 128, 1536, 128, 768};
    for (int t = 0; t < 7; t++) {
        A.csrc[t] = d_in[csrc[t]];
        A.coff[t] = (int)coff[t];
        A.cn[t] = cn[t];
    }
    const int psrc[7] = {3, 6, 8, 9, 11, 12, 14};
    const long long pdst[7] = {U_WEM, U_W1N, U_W1R, U_WEN, U_WER, U_W2N, U_W2R};
    const int pK[7] = {64, 128, 128, 128, 128, 128, 128};
    for (int t = 0; t < 7; t++) {
        A.psrc[t] = d_in[psrc[t]];
        A.pdst[t] = (unsigned)pdst[t];
        A.pK[t] = pK[t];
    }
    A.sp2 = d_in[23];
    A.sc2 = d_in[24];
    A.b1src = d_in[18];
    A.swsp = d_in[19];
    A.swsc = d_in[20];
    prep_kernel<<<512, 256, 0, stream>>>(A, wsf, wsi, fbase, gdet);

    const int* ei_ue = (const int*)d_in[1];
    const int* ei_eu = (const int*)d_in[2];

    hist_both<<<2048, 256, 0, stream>>>(ei_ue, ei_eu, wsi + I_CNT_UE, wsi + I_CNT_EU);
    scan1_both<<<294, 256, 0, stream>>>(wsi + I_CNT_UE, wsi + I_RO_UE, wsi + I_BSUM_UE,
                                        wsi + I_CNT_EU, wsi + I_RO_EU, wsi + I_BSUM_EU);
    scan2_both<<<2, 256, 0, stream>>>(wsi + I_BSUM_UE, wsi + I_BOFF_UE, wsi + I_BSUM_EU, wsi + I_BOFF_EU);
    scan3_both<<<512, 256, 0, stream>>>(wsi + I_RO_UE, wsi + I_CUR_UE, wsi + I_BOFF_UE,
                                        wsi + I_RO_EU, wsi + I_CUR_EU, wsi + I_BOFF_EU);
    fill_both<<<2048, 256, 0, stream>>>(ei_ue, ei_eu, wsi + I_CUR_UE, wsi + I_SRT_UE,
                                        wsi + I_CUR_EU, wsi + I_SRT_EU);

    // xe = x_email @ w_email^T + b_email -> B0
    lin_xe<<<3125, 256, 0, stream>>>(d_in[0], fbase + U_WEM, wsf + O_BEM, wsf + O_B0, kNE, gdet);

    // e1 = relu(mean_ue(emb) @ W1n + xe @ W1r + b) -> B1
    agglin_mfma<true, false><<<3125, 512, 0, stream>>>(
        d_in[5], wsf + O_B0, fbase + U_W1N, fbase + U_W1R, wsf + O_BL1, wsf + O_B1,
        wsi + I_RO_UE, wsi + I_CNT_UE, wsi + I_SRT_UE, kNE, gdet);

    // u1 = relu(mean_eu(xe) @ Wen + emb @ Wer + b) -> B2
    agglin_mfma<false, true><<<1563, 512, 0, stream>>>(
        wsf + O_B0, d_in[5], fbase + U_WEN, fbase + U_WER, wsf + O_BEN, wsf + O_B2,
        wsi + I_RO_EU, wsi + I_CNT_EU, wsi + I_SRT_EU, kNU, gdet);

    // e2 = relu(mean_ue(u1) @ W2n + e1 @ W2r + b) -> B0 (xe dead)
    agglin_mfma<false, false><<<3125, 512, 0, stream>>>(
        wsf + O_B2, wsf + O_B1, fbase + U_W2N, fbase + U_W2R, wsf + O_BL2, wsf + O_B0,
        wsi + I_RO_UE, wsi + I_CNT_UE, wsi + I_SRT_UE, kNE, gdet);

    // h = kan1(e2) -> B1;  out = kan2(h)
    kan1_mfma<<<3125, 512, 0, stream>>>(wsf + O_B0, fbase + U_BASE1, fbase + U_SW1H, fbase + U_SW1L,
                                        wsf + O_GRID1, wsf + O_B1);
    kan2_kernel<<<2048, 256, 0, stream>>>(wsf + O_B1, wsf + O_BASE2, wsf + O_SW2, wsf + O_GRID2, d_out, gdet);
}

// Round 13
// 922.669 us; speedup vs baseline: 1.7666x; 1.7666x over previous
//
#include <hip/hip_runtime.h>
#include <hip/hip_bf16.h>

typedef __attribute__((ext_vector_type(8))) short short8;
typedef __attribute__((ext_vector_type(4))) float f32x4;

// ---------------- problem constants ----------------
static constexpr int kNE  = 200000;   // emails
static constexpr int kNU  = 100000;   // users
static constexpr int kE   = 1000000;  // edges per type
static constexpr int kGrpU = kNE / 8; // 25000 (exact)
static constexpr int kGrpE = kNU / 8; // 12500 (exact)

// ---------------- workspace layout (4-byte element offsets) ----------------
// HARD CONSTRAINT (r5, r7): ws_size = 256 MiB = 268,435,456 B.
static constexpr long long SZ_NEH = (long long)kNE * 128;  // 25.6M
static constexpr long long SZ_NUH = (long long)kNU * 128;  // 12.8M
static constexpr long long O_B0   = 64;
static constexpr long long O_B1   = O_B0 + SZ_NEH;
static constexpr long long O_B2   = O_B1 + SZ_NEH;
static constexpr long long O_W    = O_B2 + SZ_NUH;
static constexpr long long O_BEM  = O_W;                   // 128
static constexpr long long O_BL1  = O_BEM + 128;           // 128
static constexpr long long O_BEN  = O_BL1 + 128;           // 128
static constexpr long long O_BL2  = O_BEN + 128;           // 128
static constexpr long long O_GRID1= O_BL2 + 128;           // 1536
static constexpr long long O_BASE2= O_GRID1 + 1536;        // 128
static constexpr long long O_GRID2= O_BASE2 + 128;         // 768
static constexpr long long O_SW2  = O_GRID2 + 768;         // 1024
// int region
static constexpr long long I_CNT_UE = O_SW2 + 1024;
static constexpr long long I_CNT_EU = I_CNT_UE + kNE;
static constexpr long long I_RO_UE  = I_CNT_EU + kNU;
static constexpr long long I_RO_EU  = I_RO_UE + kNE;
static constexpr long long I_CUR_UE = I_RO_EU + kNU;
static constexpr long long I_CUR_EU = I_CUR_UE + kNE;
static constexpr long long I_SRT_UE = I_CUR_EU + kNU;
static constexpr long long I_SRT_EU = I_SRT_UE + kE;
static constexpr long long I_BSUM_UE= I_SRT_EU + kE;
static constexpr long long I_BOFF_UE= I_BSUM_UE + 256;
static constexpr long long I_BSUM_EU= I_BOFF_UE + 256;
static constexpr long long I_BOFF_EU= I_BSUM_EU + 256;
static constexpr long long FR_BASE_I= (I_BOFF_EU + 256 + 7) & ~7LL;  // = 66,905,056
// bf16 MFMA B-fragment region (ushort offsets from fbase); total 245,760 ushorts
static constexpr long long U_WEM   = 0;
static constexpr long long U_W1N   = U_WEM + 8192;
static constexpr long long U_W1R   = U_W1N + 16384;
static constexpr long long U_WEN   = U_W1R + 16384;
static constexpr long long U_WER   = U_WEN + 16384;
static constexpr long long U_W2N   = U_WER + 16384;
static constexpr long long U_W2R   = U_W2N + 16384;
static constexpr long long U_BASE1 = U_W2R + 16384;
static constexpr long long U_SW1H  = U_BASE1 + 8192;
static constexpr long long U_SW1L  = U_SW1H + 65536;

__device__ __forceinline__ float bf2f(unsigned short u) {
    return __uint_as_float(((unsigned)u) << 16);
}
__device__ __forceinline__ unsigned short f2bf_rne(float f) {
    unsigned u = __float_as_uint(f);
    return (unsigned short)((u + 0x7fffu + ((u >> 16) & 1u)) >> 16);
}
__device__ __forceinline__ void split2(float x, unsigned short& hi, unsigned short& lo) {
    hi = f2bf_rne(x);
    lo = f2bf_rne(x - bf2f(hi));
}
// ---- r14: truncation split (activations only; weights keep rne in prep) ----
__device__ __forceinline__ float btrunc(float x) {
    return __uint_as_float(__float_as_uint(x) & 0xffff0000u);
}
// pack top-16-bits of two floats: low16 = bf16t(x0), high16 = bf16t(x1) (1 v_perm)
__device__ __forceinline__ unsigned pack_hi2(float x0, float x1) {
    return __builtin_amdgcn_perm(__float_as_uint(x1), __float_as_uint(x0), 0x07060302u);
}
// trunc-split 8 floats into hi/lo short8 fragments (8 and + 8 sub + 8 perm)
__device__ __forceinline__ void split8_trunc(const float* __restrict__ xv, short8& ah, short8& al) {
    unsigned* hp = (unsigned*)&ah;
    unsigned* lp = (unsigned*)&al;
#pragma unroll
    for (int jp = 0; jp < 4; jp++) {
        const float x0 = xv[2 * jp], x1 = xv[2 * jp + 1];
        const float l0 = x0 - btrunc(x0), l1 = x1 - btrunc(x1);
        hp[jp] = pack_hi2(x0, x1);
        lp[jp] = pack_hi2(l0, l1);
    }
}
// dtype probe: grid1[0] as fp32 is -2.2f (0xC00CCCCD); else storage is bf16.
__device__ __forceinline__ int get_isbf(const unsigned* __restrict__ g) {
    return (g[0] == 0xC00CCCCDu) ? 0 : 1;
}

// ================= fused prep (verified r9) =================
__device__ __forceinline__ void pack128_one(const void* __restrict__ src, unsigned short* __restrict__ dst,
                                            int K, int t, int isbf) {
    const int lane = t & 63;
    const int nt = (t >> 6) % 8;
    const int kt = (t >> 6) / 8;
    const int n = nt * 16 + (lane & 15);
    const int k0 = kt * 32 + (lane >> 4) * 8;
    unsigned short* d = dst + (((size_t)(kt * 8 + nt) * 64 + lane) << 3);
#pragma unroll
    for (int j = 0; j < 8; j++) {
        float f = isbf ? bf2f(((const unsigned short*)src)[(size_t)n * K + k0 + j])
                       : ((const float*)src)[(size_t)n * K + k0 + j];
        d[j] = f2bf_rne(f);
    }
}

__device__ __forceinline__ void base1_one(const void* __restrict__ src, unsigned short* __restrict__ dst,
                                          int t, int isbf) {
    const int lane = t & 63, nt = (t >> 6) & 3, kt = t >> 8;
    const int n = nt * 16 + (lane & 15);
    const int k0 = kt * 32 + (lane >> 4) * 8;
    unsigned short* d = dst + (((size_t)(kt * 4 + nt) * 64 + lane) << 3);
#pragma unroll
    for (int j = 0; j < 8; j++) {
        float f = isbf ? bf2f(((const unsigned short*)src)[n * 128 + k0 + j])
                       : ((const float*)src)[n * 128 + k0 + j];
        d[j] = f2bf_rne(f);
    }
}

__device__ __forceinline__ void sw1_one(const void* __restrict__ sp, const void* __restrict__ sc,
                                        unsigned short* __restrict__ dh, unsigned short* __restrict__ dl,
                                        int t, int isbf) {
    const int lane = t & 63, nt = (t >> 6) & 3, kt = t >> 8;
    const int n = nt * 16 + (lane & 15);
    const int k0 = kt * 32 + (lane >> 4) * 8;
    const float scal = isbf ? bf2f(((const unsigned short*)sc)[n * 128 + (k0 >> 3)])
                            : ((const float*)sc)[n * 128 + (k0 >> 3)];
    const size_t base = ((size_t)(kt * 4 + nt) * 64 + lane) << 3;
#pragma unroll
    for (int j = 0; j < 8; j++) {
        float f = isbf ? bf2f(((const unsigned short*)sp)[(size_t)n * 1024 + k0 + j])
                       : ((const float*)sp)[(size_t)n * 1024 + k0 + j];
        float p = f * scal;
        unsigned short hi, lo;
        split2(p, hi, lo);
        dh[base + j] = hi;
        dl[base + j] = lo;
    }
}

struct PrepArgs {
    const void* csrc[7];  int coff[7];  int cn[7];
    const void* psrc[7];  unsigned pdst[7];  int pK[7];
    const void* sp2;  const void* sc2;
    const void* b1src;  const void* swsp;  const void* swsc;
};

__global__ __launch_bounds__(256) void prep_kernel(PrepArgs A, float* __restrict__ wsf,
                                                   int* __restrict__ wsi,
                                                   unsigned short* __restrict__ fbase,
                                                   const unsigned* __restrict__ gdet) {
    const int isbf = get_isbf(gdet);
    const int t0 = blockIdx.x * 256 + threadIdx.x;
    const int gs = gridDim.x * 256;
    for (int i = t0; i < kNE + kNU; i += gs) wsi[I_CNT_UE + i] = 0;
    for (int t = 0; t < 7; t++) {
        const int n = A.cn[t];
        const void* s = A.csrc[t];
        float* d = wsf + A.coff[t];
        for (int i = t0; i < n; i += gs)
            d[i] = isbf ? bf2f(((const unsigned short*)s)[i]) : ((const float*)s)[i];
    }
    for (int i = t0; i < 1024; i += gs) {
        float a = isbf ? bf2f(((const unsigned short*)A.sp2)[i]) : ((const float*)A.sp2)[i];
        float b = isbf ? bf2f(((const unsigned short*)A.sc2)[i >> 3]) : ((const float*)A.sc2)[i >> 3];
        wsf[O_SW2 + i] = a * b;
    }
    for (int t = 0; t < 7; t++) {
        const int K = A.pK[t];
        const int tot = (K / 32) * 8 * 64;
        unsigned short* dst = fbase + A.pdst[t];
        const void* src = A.psrc[t];
        for (int i = t0; i < tot; i += gs) pack128_one(src, dst, K, i, isbf);
    }
    for (int i = t0; i < 1024; i += gs) base1_one(A.b1src, fbase + U_BASE1, i, isbf);
    for (int i = t0; i < 8192; i += gs)
        sw1_one(A.swsp, A.swsc, fbase + U_SW1H, fbase + U_SW1L, i, isbf);
}

// ================= fused CSR build (r17 verified: XCD-partitioned) =================
__global__ __launch_bounds__(256) void hist_both(const int* __restrict__ ue, const int* __restrict__ eu,
                                                 int* __restrict__ cntU, int* __restrict__ cntE) {
    const int g = blockIdx.x & 7;
    const int loU = g * kGrpU, hiU = loU + kGrpU;
    const int loE = g * kGrpE, hiE = loE + kGrpE;
    const int stride = (gridDim.x >> 3) * 256;
    for (int i = (blockIdx.x >> 3) * 256 + threadIdx.x; i < kE; i += stride) {
        const int d = ue[kE + i];
        if (d >= loU && d < hiU) atomicAdd(&cntU[d], 1);
        const int d2 = eu[kE + i];
        if (d2 >= loE && d2 < hiE) atomicAdd(&cntE[d2], 1);
    }
}

__global__ __launch_bounds__(256) void scan1_both(const int* __restrict__ cntU, int* __restrict__ roU,
                                                  int* __restrict__ bsU, const int* __restrict__ cntE,
                                                  int* __restrict__ roE, int* __restrict__ bsE) {
    __shared__ int sc[256];
    int b = blockIdx.x;
    const int* cnt;  int* ro;  int* bsum;  int n;
    if (b < 196) { cnt = cntU; ro = roU; bsum = bsU; n = kNE; }
    else { b -= 196; cnt = cntE; ro = roE; bsum = bsE; n = kNU; }
    const int t = threadIdx.x;
    const int i0 = b * 1024 + t * 4;
    int c[4];
#pragma unroll
    for (int q = 0; q < 4; q++) c[q] = (i0 + q < n) ? cnt[i0 + q] : 0;
    int s = c[0] + c[1] + c[2] + c[3];
    sc[t] = s;
    __syncthreads();
    for (int off = 1; off < 256; off <<= 1) {
        int v = (t >= off) ? sc[t - off] : 0;
        __syncthreads();
        sc[t] += v;
        __syncthreads();
    }
    int run = sc[t] - s;
#pragma unroll
    for (int q = 0; q < 4; q++) {
        if (i0 + q < n) ro[i0 + q] = run;
        run += c[q];
    }
    if (t == 255) bsum[b] = sc[255];
}

__global__ __launch_bounds__(256) void scan2_both(const int* __restrict__ bsU, int* __restrict__ boU,
                                                  const int* __restrict__ bsE, int* __restrict__ boE) {
    __shared__ int sc[256];
    const int* bsum;  int* boff;  int nb;
    if (blockIdx.x == 0) { bsum = bsU; boff = boU; nb = 196; }
    else { bsum = bsE; boff = boE; nb = 98; }
    const int t = threadIdx.x;
    int s = (t < nb) ? bsum[t] : 0;
    sc[t] = s;
    __syncthreads();
    for (int off = 1; off < 256; off <<= 1) {
        int v = (t >= off) ? sc[t - off] : 0;
        __syncthreads();
        sc[t] += v;
        __syncthreads();
    }
    if (t < nb) boff[t] = sc[t] - s;
}

__global__ __launch_bounds__(256) void scan3_both(int* __restrict__ roU, int* __restrict__ curU,
                                                  const int* __restrict__ boU, int* __restrict__ roE,
                                                  int* __restrict__ curE, const int* __restrict__ boE) {
    const int stride = gridDim.x * blockDim.x;
    for (int i = blockIdx.x * blockDim.x + threadIdx.x; i < kNE + kNU; i += stride) {
        if (i < kNE) {
            int v = roU[i] + boU[i >> 10];
            roU[i] = v;
            curU[i] = v;
        } else {
            int j = i - kNE;
            int v = roE[j] + boE[j >> 10];
            roE[j] = v;
            curE[j] = v;
        }
    }
}

__global__ __launch_bounds__(256) void fill_both(const int* __restrict__ ue, const int* __restrict__ eu,
                                                 int* __restrict__ curU, int* __restrict__ srtU,
                                                 int* __restrict__ curE, int* __restrict__ srtE) {
    const int g = blockIdx.x & 7;
    const int loU = g * kGrpU, hiU = loU + kGrpU;
    const int loE = g * kGrpE, hiE = loE + kGrpE;
    const int stride = (gridDim.x >> 3) * 256;
    for (int i = (blockIdx.x >> 3) * 256 + threadIdx.x; i < kE; i += stride) {
        const int d = ue[kE + i];
        if (d >= loU && d < hiU) {
            const int pos = atomicAdd(&curU[d], 1);
            srtU[pos] = ue[i];
        }
        const int d2 = eu[kE + i];
        if (d2 >= loE && d2 < hiE) {
            const int pos = atomicAdd(&curE[d2], 1);
            srtE[pos] = eu[i];
        }
    }
}

// ================= LDS staging (r12: THREADS-templated) =================
template <int KD, bool RAW, int THREADS>
__device__ __forceinline__ void stage_tile(float (*Xs)[132], const void* __restrict__ Av, int r0, int N,
                                           int tid, int isbf) {
    constexpr int TPR = THREADS / 64;   // threads per row
    constexpr int per = KD / TPR;       // floats per thread (16 or 32)
    const int row = tid / TPR;
    const int cq = (tid % TPR) * per;
    const size_t gr = (size_t)min(r0 + row, N - 1);
    if (RAW && isbf) {
        const unsigned short* p = (const unsigned short*)Av + gr * KD + cq;
#pragma unroll
        for (int v = 0; v < per; v += 8) {
            short8 s = *(const short8*)(p + v);
#pragma unroll
            for (int j = 0; j < 8; j++) Xs[row][cq + v + j] = bf2f(((unsigned short*)&s)[j]);
        }
    } else {
        const float* p = (const float*)Av + gr * KD + cq;
#pragma unroll
        for (int v = 0; v < per; v += 4) *(float4*)&Xs[row][cq + v] = *(const float4*)(p + v);
    }
}

// split-bf16 GEMM phase body (r14: trunc-split, 24 ops vs ~80 for rne-split)
template <int KT, int NT>
__device__ __forceinline__ void gemm_phase(float (*Xs)[132], const unsigned short* __restrict__ Wf,
                                           f32x4* acc, int rowl, int q, int lane, int ntBase) {
#pragma unroll
    for (int kt = 0; kt < KT; kt++) {
        float xv[8];
        *(float4*)&xv[0] = *(const float4*)&Xs[rowl][kt * 32 + q * 8];
        *(float4*)&xv[4] = *(const float4*)&Xs[rowl][kt * 32 + q * 8 + 4];
        short8 ah, al;
        split8_trunc(xv, ah, al);
#pragma unroll
        for (int nt = 0; nt < NT; nt++) {
            short8 b = *(const short8*)(Wf + (((size_t)(kt * 8 + ntBase + nt) * 64 + lane) << 3));
            acc[nt] = __builtin_amdgcn_mfma_f32_16x16x32_bf16(ah, b, acc[nt], 0, 0, 0);
            acc[nt] = __builtin_amdgcn_mfma_f32_16x16x32_bf16(al, b, acc[nt], 0, 0, 0);
        }
    }
}

// ================= lin_xe (verified r9) =================
__global__ __launch_bounds__(256) void lin_xe(const void* __restrict__ A1,
                                              const unsigned short* __restrict__ W1f,
                                              const float* __restrict__ bias, float* __restrict__ out, int N,
                                              const unsigned* __restrict__ gdet) {
    __shared__ float Xs[64][132];
    const int tid = threadIdx.x;
    const int wave = tid >> 6, lane = tid & 63;
    const int m = lane & 15, q = lane >> 4;
    const int r0 = blockIdx.x * 64;
    const int isbf = get_isbf(gdet);
    const int rowl = wave * 16 + m;
    f32x4 acc[8] = {};

    stage_tile<64, true, 256>(Xs, A1, r0, N, tid, isbf);
    __syncthreads();
    gemm_phase<2, 8>(Xs, W1f, acc, rowl, q, lane, 0);

    float bv[8];
#pragma unroll
    for (int nt = 0; nt < 8; nt++) bv[nt] = bias[nt * 16 + m];
#pragma unroll
    for (int r = 0; r < 4; r++) {
        int grow = r0 + wave * 16 + q * 4 + r;
        if (grow < N) {
#pragma unroll
            for (int nt = 0; nt < 8; nt++)
                out[(size_t)grow * 128 + nt * 16 + m] = acc[nt][r] + bv[nt];
        }
    }
}

// gather row load helper (r12)
template <bool RAWG>
__device__ __forceinline__ float2 gload(const void* __restrict__ G, int s, int lane, int isbf) {
    if (RAWG && isbf) {
        const ushort2 v = *(const ushort2*)((const unsigned short*)G + (size_t)s * 128 + lane * 2);
        return make_float2(bf2f(v.x), bf2f(v.y));
    }
    return *(const float2*)((const float*)G + (size_t)s * 128 + lane * 2);
}

// ================= fused agg + dual GEMM =================
// r12/r13/r17/r19 verified: 512-thread blocks, wave = (row-group wg) x
// (col-half wh), acc[4], per-row 4-deep edge unroll, CSR bounds preloaded.
template <bool RAWG, bool RAW2>
__global__ __launch_bounds__(512, 8) void agglin_mfma(const void* __restrict__ Gsrc, const void* __restrict__ A2,
                                                   const unsigned short* __restrict__ W1f,
                                                   const unsigned short* __restrict__ W2f,
                                                   const float* __restrict__ bias, float* __restrict__ out,
                                                   const int* __restrict__ ro, const int* __restrict__ cnt,
                                                   const int* __restrict__ sorted, int N,
                                                   const unsigned* __restrict__ gdet) {
    __shared__ float Xs[64][132];
    const int tid = threadIdx.x;
    const int wave = tid >> 6, lane = tid & 63;
    const int m = lane & 15, q = lane >> 4;
    const int wg = wave >> 1;   // row-group 0..3 (16 rows each)
    const int wh = wave & 1;    // col-half 0..1 (4 nt each)
    const int r0 = blockIdx.x * 64;
    const int isbf = get_isbf(gdet);

    // preload CSR bounds for the wave's 8 rows (r19: independent loads up-front)
    int beg8[8], cnt8[8];
#pragma unroll
    for (int rr = 0; rr < 8; rr++) {
        const int n = r0 + wave * 8 + rr;
        beg8[rr] = (n < N) ? ro[n] : 0;
        cnt8[rr] = (n < N) ? cnt[n] : 0;
    }

    // gather phase: wave w computes means of rows w*8..w*8+7 into Xs (r12 form).
#pragma unroll 1
    for (int rr = 0; rr < 8; rr++) {
        const int lrow = wave * 8 + rr;
        const int beg = beg8[rr];
        const int end = beg + cnt8[rr];
        float ax = 0.f, ay = 0.f;
        float a1x = 0.f, a1y = 0.f, a2x = 0.f, a2y = 0.f, a3x = 0.f, a3y = 0.f;
        int p = beg;
        for (; p + 3 < end; p += 4) {
            const int s0 = sorted[p], s1 = sorted[p + 1], s2 = sorted[p + 2], s3 = sorted[p + 3];
            const float2 v0 = gload<RAWG>(Gsrc, s0, lane, isbf);
            const float2 v1 = gload<RAWG>(Gsrc, s1, lane, isbf);
            const float2 v2 = gload<RAWG>(Gsrc, s2, lane, isbf);
            const float2 v3 = gload<RAWG>(Gsrc, s3, lane, isbf);
            ax += v0.x;  ay += v0.y;
            a1x += v1.x; a1y += v1.y;
            a2x += v2.x; a2y += v2.y;
            a3x += v3.x; a3y += v3.y;
        }
        for (; p < end; p++) {
            const float2 v = gload<RAWG>(Gsrc, sorted[p], lane, isbf);
            ax += v.x;
            ay += v.y;
        }
        ax += a1x + a2x + a3x;
        ay += a1y + a2y + a3y;
        const int deg = end - beg;
        const float inv = (deg > 0) ? 1.f / (float)deg : 0.f;
        Xs[lrow][lane * 2] = ax * inv;
        Xs[lrow][lane * 2 + 1] = ay * inv;
    }
    __syncthreads();

    const int rowl = wg * 16 + m;
    const int ntBase = wh * 4;
    f32x4 acc[4] = {};

    // phase 1: mean @ W1^T
    gemm_phase<4, 4>(Xs, W1f, acc, rowl, q, lane, ntBase);

    // phase 2: + A2 @ W2^T
    __syncthreads();
    stage_tile<128, RAW2, 512>(Xs, A2, r0, N, tid, isbf);
    __syncthreads();
    gemm_phase<4, 4>(Xs, W2f, acc, rowl, q, lane, ntBase);

    // epilogue
    float bv[4];
#pragma unroll
    for (int nt = 0; nt < 4; nt++) bv[nt] = bias[(ntBase + nt) * 16 + m];
#pragma unroll
    for (int r = 0; r < 4; r++) {
        int grow = r0 + wg * 16 + q * 4 + r;
        if (grow < N) {
#pragma unroll
            for (int nt = 0; nt < 4; nt++) {
                float v = acc[nt][r] + bv[nt];
                out[(size_t)grow * 128 + (ntBase + nt) * 16 + m] = fmaxf(v, 0.f);
            }
        }
    }
}

// ================= uniform-knot Cox-de Boor collapse (r11) =================
// Scalar version (kan2 uses float bases + FMA, no fragments)
__device__ __forceinline__ void bases8u(float x, float t0, float invh, float* __restrict__ b) {
    const float sp = (x - t0) * invh;
    const float fi = floorf(sp);
    const float u = sp - fi;
    const int i = (int)fi;
    const float u2 = u * u, u3 = u2 * u;
    const float v = 1.f - u;
    const float p0 = u3 * (1.f / 6.f);
    const float p1 = fmaf(-0.5f, u3, fmaf(0.5f, u2, fmaf(0.5f, u, 1.f / 6.f)));
    const float p2 = fmaf(0.5f, u3, fmaf(-1.f, u2, 2.f / 3.f));
    const float p3 = v * v * v * (1.f / 6.f);
#pragma unroll
    for (int j = 0; j < 8; j++) {
        float r = (i == j) ? p0 : 0.f;
        r = (i == j + 1) ? p1 : r;
        r = (i == j + 2) ? p2 : r;
        r = (i == j + 3) ? p3 : r;
        b[j] = r;
    }
}

// ---- r15: fragment-direct funnel-shift scatter (verified r15 run) ----
__device__ __forceinline__ void bases8u_frag(float x, float t0, float invh, short8& bh, short8& bl) {
    const float sp = (x - t0) * invh;
    const float fi = floorf(sp);
    const float u = sp - fi;
    int i = (int)fi;
    i = max(-1, min(11, i));
    const float u2 = u * u, u3 = u2 * u;
    const float v = 1.f - u;
    const float p0 = u3 * (1.f / 6.f);
    const float p1 = fmaf(-0.5f, u3, fmaf(0.5f, u2, fmaf(0.5f, u, 1.f / 6.f)));
    const float p2 = fmaf(0.5f, u3, fmaf(-1.f, u2, 2.f / 3.f));
    const float p3 = v * (v * v) * (1.f / 6.f);
    const float q0 = p0 - btrunc(p0), q1 = p1 - btrunc(p1);
    const float q2 = p2 - btrunc(p2), q3 = p3 - btrunc(p3);
    // little-endian: bits[0:15]=p3, [16:31]=p2, [32:47]=p1, [48:63]=p0
    const unsigned long long Ph = (((unsigned long long)pack_hi2(p1, p0)) << 32) | pack_hi2(p3, p2);
    const unsigned long long Pl = (((unsigned long long)pack_hi2(q1, q0)) << 32) | pack_hi2(q3, q2);
    const int t = 16 * i - 48;  // in [-64, 128], multiple of 16
    const unsigned sa = (unsigned)t & 63u;
    const unsigned sb = (unsigned)(-t) & 63u;
    const unsigned sc = (unsigned)(64 - t) & 63u;
    const unsigned sd = (unsigned)(t - 64) & 63u;
    const bool neg = t < 0;
    const bool ok0 = t >= -48;
    const bool lt64 = t < 64;
    const bool gt0 = t > 0;
    const bool lt128 = t < 128;
    const unsigned long long h0 = neg ? (ok0 ? (Ph >> sb) : 0ull) : (lt64 ? (Ph << sa) : 0ull);
    const unsigned long long h1 = neg ? 0ull : (lt64 ? (gt0 ? (Ph >> sc) : 0ull)
                                                     : (lt128 ? (Ph << sd) : 0ull));
    const unsigned long long g0 = neg ? (ok0 ? (Pl >> sb) : 0ull) : (lt64 ? (Pl << sa) : 0ull);
    const unsigned long long g1 = neg ? 0ull : (lt64 ? (gt0 ? (Pl >> sc) : 0ull)
                                                     : (lt128 ? (Pl << sd) : 0ull));
    unsigned long long* bhp = (unsigned long long*)&bh;
    unsigned long long* blp = (unsigned long long*)&bl;
    bhp[0] = h0; bhp[1] = h1;
    blp[0] = g0; blp[1] = g1;
}

// ================= KAN layer 1 =================
// r19-verified version (150 us, 60 VGPR): 256 threads, XOR-swizzled unpadded
// LDS [64][128], trunc-split, funnel-shift fragment bases, phase-B register
// ping-pong weight prefetch. r20's K-split (512,8) REVERTED: the 64-VGPR cap
// spilled the ~100-VGPR pipeline to scratch (VGPR=32, 3.7GB HBM spill traffic,
// 848 us). Occupancy push and deep register prefetch are mutually exclusive here.
__global__ __launch_bounds__(256) void kan1_mfma(const float* __restrict__ X,
                                                 const unsigned short* __restrict__ basef,
                                                 const unsigned short* __restrict__ swh,
                                                 const unsigned short* __restrict__ swl,
                                                 const float* __restrict__ grid, float* __restrict__ Hout) {
    __shared__ float Xs[64][128];
    const int tid = threadIdx.x;
    const int wave = tid >> 6, lane = tid & 63;
    const int m = lane & 15, q = lane >> 4;
    const int r0 = blockIdx.x * 64;

    const float t0 = grid[0];
    const float invh = 1.f / (grid[1] - grid[0]);

    {
        const int row = tid >> 2, cq = (tid & 3) * 32;
        const int sw = (row & 7) << 2;
        const float* p = &X[(size_t)(r0 + row) * 128 + cq];
#pragma unroll
        for (int v = 0; v < 8; v++) *(float4*)&Xs[row][(cq + v * 4) ^ sw] = *(const float4*)(p + v * 4);
    }
    __syncthreads();

    const int rowl = wave * 16 + m;
    const int swr = (rowl & 7) << 2;
    f32x4 acc[4] = {};

    // phase A: silu(x) @ base1^T (K=128), trunc-split A, exact-bf16 W
#pragma unroll
    for (int kt = 0; kt < 4; kt++) {
        float xv[8];
        *(float4*)&xv[0] = *(const float4*)&Xs[rowl][(kt * 32 + q * 8) ^ swr];
        *(float4*)&xv[4] = *(const float4*)&Xs[rowl][(kt * 32 + q * 8 + 4) ^ swr];
        float sv[8];
#pragma unroll
        for (int j = 0; j < 8; j++) {
            float x = xv[j];
            sv[j] = x / (1.f + __expf(-x));
        }
        short8 ah, al;
        split8_trunc(sv, ah, al);
#pragma unroll
        for (int nt = 0; nt < 4; nt++) {
            short8 b = *(const short8*)(basef + (((size_t)(kt * 4 + nt) * 64 + lane) << 3));
            acc[nt] = __builtin_amdgcn_mfma_f32_16x16x32_bf16(ah, b, acc[nt], 0, 0, 0);
            acc[nt] = __builtin_amdgcn_mfma_f32_16x16x32_bf16(al, b, acc[nt], 0, 0, 0);
        }
    }

    // phase B: spline GEMM (K=1024). Ping-pong prefetched weight registers.
    // Fragment address (kt,nt): (kt*2048 + nt*512 + lane*8) ushorts.
    const unsigned short* __restrict__ whp = swh + ((size_t)lane << 3);
    const unsigned short* __restrict__ wlp = swl + ((size_t)lane << 3);
    short8 wAh[4], wAl[4], wBh[4], wBl[4];
#pragma unroll
    for (int nt = 0; nt < 4; nt++) {
        wAh[nt] = *(const short8*)(whp + nt * 512);
        wAl[nt] = *(const short8*)(wlp + nt * 512);
    }
    float xE = Xs[rowl][q ^ swr];
#pragma unroll 1
    for (int kt2 = 0; kt2 < 16; kt2++) {
        const int ko = 2 * kt2 + 1;
        // prefetch odd-kt weights (independent of even compute below)
#pragma unroll
        for (int nt = 0; nt < 4; nt++) {
            wBh[nt] = *(const short8*)(whp + ko * 2048 + nt * 512);
            wBl[nt] = *(const short8*)(wlp + ko * 2048 + nt * 512);
        }
        const float xO = Xs[rowl][(ko * 4 + q) ^ swr];
        // compute even kt with buffer A
        {
            short8 bh, bl;
            bases8u_frag(xE, t0, invh, bh, bl);
#pragma unroll
            for (int nt = 0; nt < 4; nt++) {
                acc[nt] = __builtin_amdgcn_mfma_f32_16x16x32_bf16(bh, wAh[nt], acc[nt], 0, 0, 0);
                acc[nt] = __builtin_amdgcn_mfma_f32_16x16x32_bf16(bl, wAh[nt], acc[nt], 0, 0, 0);
                acc[nt] = __builtin_amdgcn_mfma_f32_16x16x32_bf16(bh, wAl[nt], acc[nt], 0, 0, 0);
            }
        }
        // prefetch next even-kt weights
        if (kt2 < 15) {
            const int ke2 = 2 * kt2 + 2;
#pragma unroll
            for (int nt = 0; nt < 4; nt++) {
                wAh[nt] = *(const short8*)(whp + ke2 * 2048 + nt * 512);
                wAl[nt] = *(const short8*)(wlp + ke2 * 2048 + nt * 512);
            }
            xE = Xs[rowl][(ke2 * 4 + q) ^ swr];
        }
        // compute odd kt with buffer B
        {
            short8 bh, bl;
            bases8u_frag(xO, t0, invh, bh, bl);
#pragma unroll
            for (int nt = 0; nt < 4; nt++) {
                acc[nt] = __builtin_amdgcn_mfma_f32_16x16x32_bf16(bh, wBh[nt], acc[nt], 0, 0, 0);
                acc[nt] = __builtin_amdgcn_mfma_f32_16x16x32_bf16(bl, wBh[nt], acc[nt], 0, 0, 0);
                acc[nt] = __builtin_amdgcn_mfma_f32_16x16x32_bf16(bh, wBl[nt], acc[nt], 0, 0, 0);
            }
        }
    }

#pragma unroll
    for (int r = 0; r < 4; r++) {
        int grow = r0 + wave * 16 + q * 4 + r;
#pragma unroll
        for (int nt = 0; nt < 4; nt++) Hout[(size_t)grow * 64 + nt * 16 + m] = acc[nt][r];
    }
}

// ================= KAN layer 2 =================
__global__ __launch_bounds__(256) void kan2_kernel(const float* __restrict__ h, const float* __restrict__ base2,
                                                   const float* __restrict__ sw2, const float* __restrict__ grid2,
                                                   void* __restrict__ out, const unsigned* __restrict__ gdet) {
    const int lane = threadIdx.x & 63;
    const int wid = (blockIdx.x * blockDim.x + threadIdx.x) >> 6;
    const int nw = (gridDim.x * blockDim.x) >> 6;
    const int k = lane;
    const float t0 = grid2[0];
    const float invh = 1.f / (grid2[1] - grid2[0]);
    const float wb0 = base2[k], wb1 = base2[64 + k];
    float ws0[8], ws1[8];
#pragma unroll
    for (int j = 0; j < 8; j++) { ws0[j] = sw2[k * 8 + j]; ws1[j] = sw2[512 + k * 8 + j]; }
    const int isbf = get_isbf(gdet);

    for (int n = wid; n < kNE; n += nw) {
        float x = h[(size_t)n * 64 + k];
        float sil = x / (1.f + __expf(-x));
        float b[8];
        bases8u(x, t0, invh, b);
        float o0 = sil * wb0, o1 = sil * wb1;
#pragma unroll
        for (int j = 0; j < 8; j++) {
            o0 = fmaf(b[j], ws0[j], o0);
            o1 = fmaf(b[j], ws1[j], o1);
        }
#pragma unroll
        for (int off = 32; off > 0; off >>= 1) {
            o0 += __shfl_down(o0, off, 64);
            o1 += __shfl_down(o1, off, 64);
        }
        if (lane == 0) {
            if (isbf) {
                __hip_bfloat16* ob = (__hip_bfloat16*)out;
                ob[(size_t)n * 2] = __float2bfloat16(o0);
                ob[(size_t)n * 2 + 1] = __float2bfloat16(o1);
            } else {
                ((float2*)out)[n] = make_float2(o0, o1);
            }
        }
    }
}

// ================= launch =================
extern "C" void kernel_launch(void* const* d_in, const int* in_sizes, int n_in, void* d_out, int out_size,
                              void* d_ws, size_t ws_size, hipStream_t stream) {
    (void)in_sizes; (void)n_in; (void)out_size; (void)ws_size;
    float* wsf = (float*)d_ws;
    int* wsi = (int*)d_ws;
    unsigned short* fbase = (unsigned short*)(wsi + FR_BASE_I);
    const unsigned* gdet = (const unsigned*)d_in[21];

    PrepArgs A;
    const int csrc[7] = {4, 7, 10, 13, 21, 22, 25};
    const long long coff[7] = {O_BEM, O_BL1, O_BEN, O_BL2, O_GRID1, O_BASE2, O_GRID2};
    const int cn[7] = {128, 128, 128, 128, 1536, 128, 768};
    for (int t = 0; t < 7; t++) {
        A.csrc[t] = d_in[csrc[t]];
        A.coff[t] = (int)coff[t];
        A.cn[t] = cn[t];
    }
    const int psrc[7] = {3, 6, 8, 9, 11, 12, 14};
    const long long pdst[7] = {U_WEM, U_W1N, U_W1R, U_WEN, U_WER, U_W2N, U_W2R};
    const int pK[7] = {64, 128, 128, 128, 128, 128, 128};
    for (int t = 0; t < 7; t++) {
        A.psrc[t] = d_in[psrc[t]];
        A.pdst[t] = (unsigned)pdst[t];
        A.pK[t] = pK[t];
    }
    A.sp2 = d_in[23];
    A.sc2 = d_in[24];
    A.b1src = d_in[18];
    A.swsp = d_in[19];
    A.swsc = d_in[20];
    prep_kernel<<<512, 256, 0, stream>>>(A, wsf, wsi, fbase, gdet);

    const int* ei_ue = (const int*)d_in[1];
    const int* ei_eu = (const int*)d_in[2];

    hist_both<<<2048, 256, 0, stream>>>(ei_ue, ei_eu, wsi + I_CNT_UE, wsi + I_CNT_EU);
    scan1_both<<<294, 256, 0, stream>>>(wsi + I_CNT_UE, wsi + I_RO_UE, wsi + I_BSUM_UE,
                                        wsi + I_CNT_EU, wsi + I_RO_EU, wsi + I_BSUM_EU);
    scan2_both<<<2, 256, 0, stream>>>(wsi + I_BSUM_UE, wsi + I_BOFF_UE, wsi + I_BSUM_EU, wsi + I_BOFF_EU);
    scan3_both<<<512, 256, 0, stream>>>(wsi + I_RO_UE, wsi + I_CUR_UE, wsi + I_BOFF_UE,
                                        wsi + I_RO_EU, wsi + I_CUR_EU, wsi + I_BOFF_EU);
    fill_both<<<2048, 256, 0, stream>>>(ei_ue, ei_eu, wsi + I_CUR_UE, wsi + I_SRT_UE,
                                        wsi + I_CUR_EU, wsi + I_SRT_EU);

    // xe = x_email @ w_email^T + b_email -> B0
    lin_xe<<<3125, 256, 0, stream>>>(d_in[0], fbase + U_WEM, wsf + O_BEM, wsf + O_B0, kNE, gdet);

    // e1 = relu(mean_ue(emb) @ W1n + xe @ W1r + b) -> B1
    agglin_mfma<true, false><<<3125, 512, 0, stream>>>(
        d_in[5], wsf + O_B0, fbase + U_W1N, fbase + U_W1R, wsf + O_BL1, wsf + O_B1,
        wsi + I_RO_UE, wsi + I_CNT_UE, wsi + I_SRT_UE, kNE, gdet);

    // u1 = relu(mean_eu(xe) @ Wen + emb @ Wer + b) -> B2
    agglin_mfma<false, true><<<1563, 512, 0, stream>>>(
        wsf + O_B0, d_in[5], fbase + U_WEN, fbase + U_WER, wsf + O_BEN, wsf + O_B2,
        wsi + I_RO_EU, wsi + I_CNT_EU, wsi + I_SRT_EU, kNU, gdet);

    // e2 = relu(mean_ue(u1) @ W2n + e1 @ W2r + b) -> B0 (xe dead)
    agglin_mfma<false, false><<<3125, 512, 0, stream>>>(
        wsf + O_B2, wsf + O_B1, fbase + U_W2N, fbase + U_W2R, wsf + O_BL2, wsf + O_B0,
        wsi + I_RO_UE, wsi + I_CNT_UE, wsi + I_SRT_UE, kNE, gdet);

    // h = kan1(e2) -> B1;  out = kan2(h)
    kan1_mfma<<<3125, 256, 0, stream>>>(wsf + O_B0, fbase + U_BASE1, fbase + U_SW1H, fbase + U_SW1L,
                                        wsf + O_GRID1, wsf + O_B1);
    kan2_kernel<<<2048, 256, 0, stream>>>(wsf + O_B1, wsf + O_BASE2, wsf + O_SW2, wsf + O_GRID2, d_out, gdet);
}